// Round 5
// baseline (140.631 us; speedup 1.0000x reference)
//
#include <hip/hip_runtime.h>
#include <hip/hip_bf16.h>

#define NUM_USER 100000
#define K_NEIGH 32
#define DIM 64

typedef float floatx2 __attribute__((ext_vector_type(2)));
typedef float floatx4 __attribute__((ext_vector_type(4)));
typedef unsigned int uintx2 __attribute__((ext_vector_type(2)));

// Kernel 1: compress fp32 features -> packed bf16x2 table in d_ws.
// table[u*32 + j] packs dims {2j (low 16), 2j+1 (high 16)} with RNE rounding.
__global__ __launch_bounds__(256) void convert_bf16_kernel(
    const floatx2* __restrict__ feat2,   // 3.2M float2
    unsigned int*  __restrict__ table) { // 3.2M packed bf16x2
  int i = blockIdx.x * blockDim.x + threadIdx.x;
  if (i >= NUM_USER * DIM / 2) return;
  floatx2 f = feat2[i];
  unsigned int ux = __float_as_uint(f.x);
  unsigned int uy = __float_as_uint(f.y);
  // round-to-nearest-even to bf16
  unsigned int bx = (ux + 0x7fffu + ((ux >> 16) & 1u)) >> 16;
  unsigned int by = (uy + 0x7fffu + ((uy >> 16) & 1u)) >> 16;
  table[i] = bx | (by << 16);
}

// Kernel 2: gather+weighted-sum from the bf16 table.
// 16 lanes per user (4 users/wave); each lane owns dims {4*d4 .. 4*d4+3},
// loading one uint2 (8B = 4 bf16) per neighbor -> 128B line per 16-lane group.
__global__ __launch_bounds__(256) void user_graph_gather_bf16_kernel(
    const uintx2* __restrict__ table2,   // [NUM_USER][16] bf16x4 chunks
    const int*    __restrict__ graph,    // [NUM_USER][32]
    const float*  __restrict__ matrix,   // [NUM_USER][32]
    floatx4*      __restrict__ out4) {   // [NUM_USER][16] float4
  int t  = blockIdx.x * blockDim.x + threadIdx.x;
  int u  = t >> 4;
  int d4 = t & 15;
  if (u >= NUM_USER) return;

  const int*   g = graph  + u * K_NEIGH;
  const float* w = matrix + u * K_NEIGH;

  float a0 = 0.f, a1 = 0.f, a2 = 0.f, a3 = 0.f;
#pragma unroll
  for (int k = 0; k < K_NEIGH; ++k) {
    int   idx = g[k];                        // uniform per 16-lane group (L1 hit)
    float wk  = w[k];
    uintx2 p  = table2[idx * 16 + d4];       // 16 lanes x 8B = one 128B line
    float f0 = __uint_as_float(p.x << 16);
    float f1 = __uint_as_float(p.x & 0xffff0000u);
    float f2 = __uint_as_float(p.y << 16);
    float f3 = __uint_as_float(p.y & 0xffff0000u);
    a0 += wk * f0;
    a1 += wk * f1;
    a2 += wk * f2;
    a3 += wk * f3;
  }
  floatx4 r; r.x = a0; r.y = a1; r.z = a2; r.w = a3;
  out4[u * 16 + d4] = r;                     // 16B/lane coalesced store
}

// Fallback (no ws space): round-1 fp32 gather, known-good.
__global__ __launch_bounds__(256) void user_graph_gather_f32_kernel(
    const float* __restrict__ features,
    const int*   __restrict__ graph,
    const float* __restrict__ matrix,
    float*       __restrict__ out) {
  int t = blockIdx.x * blockDim.x + threadIdx.x;
  int u = t >> 6;
  int d = t & 63;
  if (u >= NUM_USER) return;
  const int*   g = graph  + (size_t)u * K_NEIGH;
  const float* w = matrix + (size_t)u * K_NEIGH;
  float acc = 0.f;
#pragma unroll
  for (int k = 0; k < K_NEIGH; ++k)
    acc += w[k] * features[(size_t)g[k] * DIM + d];
  out[(size_t)u * DIM + d] = acc;
}

extern "C" void kernel_launch(void* const* d_in, const int* in_sizes, int n_in,
                              void* d_out, int out_size, void* d_ws, size_t ws_size,
                              hipStream_t stream) {
  const float* features = (const float*)d_in[0];
  const int*   graph    = (const int*)d_in[1];
  const float* matrix   = (const float*)d_in[2];

  const size_t table_bytes = (size_t)NUM_USER * DIM * 2;  // 12.8 MB bf16
  if (ws_size >= table_bytes) {
    unsigned int* table = (unsigned int*)d_ws;
    const int n_pack = NUM_USER * DIM / 2;   // 3.2M
    convert_bf16_kernel<<<(n_pack + 255) / 256, 256, 0, stream>>>(
        (const floatx2*)features, table);
    const int total = NUM_USER * 16;         // 1.6M threads
    user_graph_gather_bf16_kernel<<<(total + 255) / 256, 256, 0, stream>>>(
        (const uintx2*)table, graph, matrix, (floatx4*)d_out);
  } else {
    const int total = NUM_USER * DIM;
    user_graph_gather_f32_kernel<<<(total + 255) / 256, 256, 0, stream>>>(
        features, graph, matrix, (float*)d_out);
  }
}